// Round 11
// baseline (341.705 us; speedup 1.0000x reference)
//
#include <hip/hip_runtime.h>
#include <math.h>

#define HEADS 8
#define C 256
#define NUM_STAR 4
#define SLOTS 32              // NUM_STAR * HEADS
#define RSQRT_DH 0.17677669529663688f   // 1/sqrt(32)
#define LN_EPS 1e-5f
#define PF 16                 // partitions per graph (grid = G*PF = 512 = 2/CU)
#define NT 32                 // nodes per block round
#define FS 260                // fbuf row stride (floats)
#define EP2 40                // e row stride (ushorts)

typedef __attribute__((ext_vector_type(8))) short short8;    // bf16x8 MFMA operand
typedef __attribute__((ext_vector_type(4))) float floatx4;   // f32x4 MFMA accum

typedef const unsigned int __attribute__((address_space(1)))* gp1_t;
typedef unsigned int __attribute__((address_space(3)))* lp3_t;

// f32 -> bf16 (RNE) top-16 (scalar)
__device__ __forceinline__ unsigned int f2b(float f) {
    unsigned int u = __float_as_uint(f);
    return (u + 0x7fffu + ((u >> 16) & 1u)) >> 16;
}
// packed f32x2 -> bf16x2 (RNE): lo -> [15:0], hi -> [31:16]
__device__ __forceinline__ unsigned int pk_bf16(float lo, float hi) {
    unsigned int r;
    asm("v_cvt_pk_bf16_f32 %0, %1, %2" : "=v"(r) : "v"(lo), "v"(hi));
    return r;
}
// async global->LDS, 16B per lane (dest base wave-uniform, + lane*16 implicit)
__device__ __forceinline__ void gld_lds16(const float* g, float* l) {
    __builtin_amdgcn_global_load_lds((gp1_t)(const void*)g, (lp3_t)(void*)l, 16, 0, 0);
}
// raw barrier: LDS-visible, does NOT drain vmcnt
__device__ __forceinline__ void block_sync_lds() {
    asm volatile("s_waitcnt lgkmcnt(0)" ::: "memory");
    __builtin_amdgcn_sched_barrier(0);
    __builtin_amdgcn_s_barrier();
    __builtin_amdgcn_sched_barrier(0);
}

// ---------------- star prep (+ gstart fold in last block) -------------------
__global__ void k_star_prep(const float* __restrict__ stars,
                            const float* __restrict__ Wq_w, const float* __restrict__ Wq_b,
                            const float* __restrict__ Wk_w, const float* __restrict__ Wk_b,
                            unsigned short* __restrict__ U16, float* __restrict__ eself,
                            float* __restrict__ denom,
                            const int* __restrict__ batch, int N, int G,
                            int* __restrict__ gstart) {
    if (blockIdx.x == gridDim.x - 1) {       // gstart block
        int g = threadIdx.x;
        if (g > G) return;
        if (g == 0) { gstart[0] = 0; return; }
        if (g == G) { gstart[G] = N; return; }
        int lo = 0, hi = N;
        while (lo < hi) {
            int mid = (lo + hi) >> 1;
            if (batch[mid] < g) lo = mid + 1; else hi = mid;
        }
        gstart[g] = lo;
        return;
    }

    __shared__ float xs[C];
    __shared__ float qv[C];
    __shared__ float kv[C];
    const int gs = blockIdx.x;           // g*4 + s
    const int g = gs >> 2, s = gs & 3;
    const int t = threadIdx.x;

    xs[t] = stars[gs * C + t];
    __syncthreads();

    float aq = Wq_b[t], ak = Wk_b[t];
    const float* wq = Wq_w + (size_t)t * C;
    const float* wk = Wk_w + (size_t)t * C;
    #pragma unroll 4
    for (int j = 0; j < C; j += 4) {
        float4 x4 = *(const float4*)(xs + j);
        float4 a4 = *(const float4*)(wq + j);
        aq += a4.x * x4.x + a4.y * x4.y + a4.z * x4.z + a4.w * x4.w;
        float4 b4 = *(const float4*)(wk + j);
        ak += b4.x * x4.x + b4.y * x4.y + b4.z * x4.z + b4.w * x4.w;
    }
    qv[t] = aq; kv[t] = ak;
    __syncthreads();

    {   // self score per head
        float p = qv[t] * kv[t];
        #pragma unroll
        for (int off = 16; off; off >>= 1) p += __shfl_down(p, off, 32);
        if ((t & 31) == 0) {
            int h = t >> 5;
            float e = __expf(p * RSQRT_DH);
            eself[g * SLOTS + s * HEADS + h] = e;
            denom[g * SLOTS + s * HEADS + h] = e;   // init with self term
        }
    }

    // U_t bf16: U16[g][slot=s*8+h][c]
    {
        const int c = t;
        #pragma unroll
        for (int h = 0; h < HEADS; ++h) {
            float u = 0.f;
            #pragma unroll
            for (int d = 0; d < 32; ++d)
                u += Wk_w[(size_t)(h * 32 + d) * C + c] * qv[h * 32 + d];
            U16[((size_t)g * SLOTS + s * HEADS + h) * C + c] =
                (unsigned short)f2b(u * RSQRT_DH);
        }
    }
}

// ---------------- fused MFMA kernel (templated for ablation) ----------------
// MODE 0: full (real). 1: no PV. 2: no QK^T/exp. 3: DMA+sync only.
template<int MODE, int REP>
__global__ __launch_bounds__(256, 2)
void k_fused(const float* __restrict__ nodes, const unsigned short* __restrict__ U16,
             const int* __restrict__ gstart, float* __restrict__ denom,
             float* __restrict__ Ypart) {
    __shared__ float          fbuf[2][NT][FS];   // 66,560 B  f32 [buf][n][c]
    __shared__ unsigned short el[SLOTS * EP2];   //  2,560 B  e [s][n]

    const int g = blockIdx.x / PF, pb = blockIdx.x % PF;
    const int t = threadIdx.x;
    const int wv = t >> 6;        // wave 0..3
    const int l  = t & 63;
    const int lr = l & 15;
    const int q  = l >> 4;
    const int st = wv & 1;        // QK^T slot-tile
    const int ng = wv >> 1;       // QK^T node-group

    const int glo = gstart[g], ghi = gstart[g + 1];
    const int len = ghi - glo;
    const int Lb = (len + PF - 1) / PF;
    const int blo = glo + pb * Lb;
    const int bhi = min(blo + Lb, ghi);
    const int nrw = (bhi > blo) ? (bhi - blo + NT - 1) / NT : 0;

    const floatx4 z4 = {0.f, 0.f, 0.f, 0.f};
    floatx4 yacc[2][4];           // [st2][ct]: Y[st2*16+q*4+r][wv*64+ct*16+lr]
    #pragma unroll
    for (int a = 0; a < 2; ++a)
        #pragma unroll
        for (int b = 0; b < 4; ++b) yacc[a][b] = z4;
    float dsum[4];
    #pragma unroll
    for (int i = 0; i < 4; ++i) dsum[i] = 0.f;

    if (nrw > 0) {
        // ---- U_t fragments for own slot-tile only (32 VGPR) ----
        short8 ureg[8];
        if (MODE == 0 || MODE == 1) {
            const unsigned short* ug = U16 + (size_t)g * SLOTS * C;
            #pragma unroll
            for (int kt = 0; kt < 8; ++kt)
                ureg[kt] = *(const short8*)&ug[(st * 16 + lr) * C + q * 8 + kt * 32];
        }
        asm volatile("s_waitcnt vmcnt(0)" ::: "memory");   // clean vmcnt base

        // DMA-issue round r into fbuf[r&1]: wave stages rows wv*8..wv*8+7
        auto issue = [&](int r) {
            const int buf = r & 1;
            #pragma unroll
            for (int i = 0; i < 8; ++i) {
                int row = wv * 8 + i;
                int gn = blo + r * NT + row;
                if (gn >= bhi) gn = blo;              // clamped dup; e masked to 0
                gld_lds16(nodes + (size_t)gn * C + l * 4, &fbuf[buf][row][0]);
            }
        };

        for (int rep = 0; rep < REP; ++rep) {
            issue(0);
            issue(1);            // outstanding: 16 per wave

            for (int rd = 0; rd < nrw; ++rd) {
                const int cur = rd & 1;
                asm volatile("s_waitcnt vmcnt(8)" ::: "memory");  // rd landed (mine)
                __builtin_amdgcn_sched_barrier(0);
                __builtin_amdgcn_s_barrier();                     // everyone's rd landed
                __builtin_amdgcn_sched_barrier(0);

                if (MODE == 0 || MODE == 1) {
                    // ---- QK^T: S[st*16+q*4+r][ng*16+lr] over K=256 ----
                    floatx4 sacc = z4;
                    {
                        const float* xr = &fbuf[cur][ng * 16 + lr][q * 8];
                        #pragma unroll
                        for (int kt = 0; kt < 8; ++kt) {
                            float4 a4 = *(const float4*)(xr + kt * 32);
                            float4 b4 = *(const float4*)(xr + kt * 32 + 4);
                            short8 bx;
                            ((unsigned int*)&bx)[0] = pk_bf16(a4.x, a4.y);
                            ((unsigned int*)&bx)[1] = pk_bf16(a4.z, a4.w);
                            ((unsigned int*)&bx)[2] = pk_bf16(b4.x, b4.y);
                            ((unsigned int*)&bx)[3] = pk_bf16(b4.z, b4.w);
                            sacc = __builtin_amdgcn_mfma_f32_16x16x32_bf16(ureg[kt], bx, sacc, 0, 0, 0);
                        }
                    }
                    // ---- exp + mask + denom + e write ----
                    {
                        const bool valid = (blo + rd * NT + ng * 16 + lr) < bhi;
                        #pragma unroll
                        for (int r = 0; r < 4; ++r) {
                            float ev = valid ? __expf(sacc[r]) : 0.f;
                            dsum[r] += ev;
                            el[(st * 16 + q * 4 + r) * EP2 + ng * 16 + lr] = (unsigned short)f2b(ev);
                        }
                    }
                }
                block_sync_lds();     // e complete; fbuf[cur] still stable

                if (MODE == 0 || MODE == 2) {
                    // ---- PV: Y[s][c] += e[s][n] * x[n][c], K=32 ----
                    short8 pa0 = *(const short8*)&el[lr * EP2 + q * 8];
                    short8 pa1 = *(const short8*)&el[(16 + lr) * EP2 + q * 8];
                    #pragma unroll
                    for (int ct = 0; ct < 4; ++ct) {
                        const int c = wv * 64 + ct * 16 + lr;
                        short8 bx;
                        const float* col = &fbuf[cur][q * 8][c];
                        ((unsigned int*)&bx)[0] = pk_bf16(col[0 * FS], col[1 * FS]);
                        ((unsigned int*)&bx)[1] = pk_bf16(col[2 * FS], col[3 * FS]);
                        ((unsigned int*)&bx)[2] = pk_bf16(col[4 * FS], col[5 * FS]);
                        ((unsigned int*)&bx)[3] = pk_bf16(col[6 * FS], col[7 * FS]);
                        yacc[0][ct] = __builtin_amdgcn_mfma_f32_16x16x32_bf16(pa0, bx, yacc[0][ct], 0, 0, 0);
                        yacc[1][ct] = __builtin_amdgcn_mfma_f32_16x16x32_bf16(pa1, bx, yacc[1][ct], 0, 0, 0);
                    }
                }
                block_sync_lds();     // PV done reading fbuf[cur] + el
                issue(rd + 2);        // reuse buffer cur for round rd+2
            }

            asm volatile("s_waitcnt vmcnt(0)" ::: "memory");  // drain trailing DMA
        }

        // ---- denom: reduce over 16 node-lanes, atomics from lr==0 ----
        #pragma unroll
        for (int i = 0; i < 4; ++i) {
            float v = dsum[i];
            v += __shfl_xor(v, 1);
            v += __shfl_xor(v, 2);
            v += __shfl_xor(v, 4);
            v += __shfl_xor(v, 8);
            dsum[i] = v;
        }
        if (lr == 0) {
            #pragma unroll
            for (int r = 0; r < 4; ++r)
                atomicAdd(&denom[g * SLOTS + st * 16 + q * 4 + r], dsum[r]);
        }
    }

    // ---- write block partial (waves own disjoint c-slices; zero if nrw==0) --
    {
        float* yg = &Ypart[(((size_t)g * PF + pb) * SLOTS) * C];
        #pragma unroll
        for (int st2 = 0; st2 < 2; ++st2)
            #pragma unroll
            for (int ct = 0; ct < 4; ++ct)
                #pragma unroll
                for (int r = 0; r < 4; ++r)
                    yg[(st2 * 16 + q * 4 + r) * C + wv * 64 + ct * 16 + lr] = yacc[st2][ct][r];
    }
}

// ---------------- pure read-BW reference (in-situ floor) --------------------
__global__ __launch_bounds__(256, 8)
void k_copy_bw(const float* __restrict__ nodes, int n4, float* __restrict__ sink) {
    const float4* p = (const float4*)nodes;
    const int S = gridDim.x * blockDim.x;
    float a0 = 0.f, a1 = 0.f, a2 = 0.f, a3 = 0.f;
    for (int rep = 0; rep < 3; ++rep) {
        int i = blockIdx.x * blockDim.x + threadIdx.x;
        for (; i + 3 * S < n4; i += 4 * S) {
            float4 v0 = p[i];
            float4 v1 = p[i + S];
            float4 v2 = p[i + 2 * S];
            float4 v3 = p[i + 3 * S];
            a0 += v0.x + v0.y + v0.z + v0.w;
            a1 += v1.x + v1.y + v1.z + v1.w;
            a2 += v2.x + v2.y + v2.z + v2.w;
            a3 += v3.x + v3.y + v3.z + v3.w;
        }
        for (; i < n4; i += S) {
            float4 v = p[i];
            a0 += v.x + v.y + v.z + v.w;
        }
    }
    float acc = (a0 + a1) + (a2 + a3);
    #pragma unroll
    for (int o = 32; o; o >>= 1) acc += __shfl_down(acc, o, 64);
    if ((threadIdx.x & 63) == 0) atomicAdd(sink, acc);
}

// ---------------- epilogue: out = LN(elu(Wv*(Ysum/denom + cself*x) + bv) + stars)
__global__ void k_epilogue(const float* __restrict__ stars,
                           const float* __restrict__ Wv_w, const float* __restrict__ Wv_b,
                           const float* __restrict__ gamma, const float* __restrict__ beta,
                           const float* __restrict__ Ypart, const float* __restrict__ eself,
                           const float* __restrict__ denom, float* __restrict__ out) {
    __shared__ float xs[C];
    __shared__ float yl[HEADS * C];
    __shared__ float cs[HEADS], ivd[HEADS], scl[HEADS];
    __shared__ float rb[8];

    const int gs = blockIdx.x;
    const int g = gs >> 2, s = gs & 3;
    const int t = threadIdx.x;

    xs[t] = stars[gs * C + t];
    if (t < HEADS) {
        float dn = denom[g * SLOTS + s * HEADS + t];
        float iv = 1.f / (dn + 1e-16f);
        ivd[t] = iv;
        cs[t] = eself[g * SLOTS + s * HEADS + t] * iv;
        scl[t] = dn * iv;
    }
    __syncthreads();

    for (int i = t; i < HEADS * C; i += 256) {
        int h = i >> 8, j = i & 255;
        float sum = 0.f;
        #pragma unroll
        for (int pbi = 0; pbi < PF; ++pbi)
            sum += Ypart[(((size_t)g * PF + pbi) * SLOTS + s * HEADS + h) * C + j];
        yl[i] = sum * ivd[h] + cs[h] * xs[j];
    }
    __syncthreads();

    const int c = t, h = c >> 5;
    float a = 0.f;
    const float* wv = Wv_w + (size_t)c * C;
    const float* yh = &yl[h * C];
    #pragma unroll 4
    for (int j = 0; j < C; j += 4) {
        float4 w4 = *(const float4*)(wv + j);
        float4 y4 = *(const float4*)(yh + j);
        a += w4.x * y4.x + w4.y * y4.y + w4.z * y4.z + w4.w * y4.w;
    }
    a += Wv_b[c] * scl[h];

    float v = a > 0.f ? a : (__expf(a) - 1.f);     // ELU
    float r = v + xs[c];                            // residual

    float ssum = r;
    #pragma unroll
    for (int off = 32; off; off >>= 1) ssum += __shfl_down(ssum, off, 64);
    const int wid = t >> 6, lane = t & 63;
    if (lane == 0) rb[wid] = ssum;
    __syncthreads();
    const float mu = (rb[0] + rb[1] + rb[2] + rb[3]) * (1.f / 256.f);
    const float d = r - mu;
    float vsum = d * d;
    #pragma unroll
    for (int off = 32; off; off >>= 1) vsum += __shfl_down(vsum, off, 64);
    if (lane == 0) rb[4 + wid] = vsum;
    __syncthreads();
    const float var = (rb[4] + rb[5] + rb[6] + rb[7]) * (1.f / 256.f);
    out[gs * C + c] = d * rsqrtf(var + LN_EPS) * gamma[c] + beta[c];
}

// ---------------------------------------------------------------------------
extern "C" void kernel_launch(void* const* d_in, const int* in_sizes, int n_in,
                              void* d_out, int out_size, void* d_ws, size_t ws_size,
                              hipStream_t stream) {
    const float* stars = (const float*)d_in[0];
    const float* nodes = (const float*)d_in[1];
    const int*   batch = (const int*)d_in[2];
    const float* Wq_w  = (const float*)d_in[3];
    const float* Wq_b  = (const float*)d_in[4];
    const float* Wk_w  = (const float*)d_in[5];
    const float* Wk_b  = (const float*)d_in[6];
    const float* Wv_w  = (const float*)d_in[7];
    const float* Wv_b  = (const float*)d_in[8];
    const float* gamma = (const float*)d_in[9];
    const float* beta  = (const float*)d_in[10];

    const int N = in_sizes[1] / C;
    const int G = in_sizes[0] / (NUM_STAR * C);

    unsigned short* U16 = (unsigned short*)d_ws;                    // G*SLOTS*C ush
    float* eself = (float*)((char*)d_ws + (size_t)G * SLOTS * C * 2);
    float* denom = eself + (size_t)G * SLOTS;
    float* Ypart = denom + (size_t)G * SLOTS;                       // G*PF*SLOTS*C f32
    int*   gstart = (int*)(Ypart + (size_t)G * PF * SLOTS * C);     // G+1
    // ---- ablation scratch (never read for output) ----
    float* denom2 = (float*)(gstart + (G + 2));
    float* Ypart2 = denom2 + (size_t)G * SLOTS;
    float* bwsink = Ypart2 + (size_t)G * PF * SLOTS * C;

    float* out = (float*)d_out;

    k_star_prep<<<G * NUM_STAR + 1, 256, 0, stream>>>(stars, Wq_w, Wq_b, Wk_w, Wk_b,
                                                      U16, eself, denom,
                                                      batch, N, G, gstart);
    // real computation (identical to round-10 kernel)
    k_fused<0, 1><<<G * PF, 256, 0, stream>>>(nodes, U16, gstart, denom, Ypart);
    k_epilogue<<<G * NUM_STAR, 256, 0, stream>>>(stars, Wv_w, Wv_b, gamma, beta,
                                                 Ypart, eself, denom, out);

    // ---- ablation probes (timing only; write scratch) ----
    k_fused<3, 3><<<G * PF, 256, 0, stream>>>(nodes, U16, gstart, denom2, Ypart2); // DMA+sync only
    k_fused<1, 3><<<G * PF, 256, 0, stream>>>(nodes, U16, gstart, denom2, Ypart2); // +QK^T/exp
    k_fused<2, 3><<<G * PF, 256, 0, stream>>>(nodes, U16, gstart, denom2, Ypart2); // +PV only
    k_copy_bw<<<2048, 256, 0, stream>>>(nodes, N * C / 4, bwsink);                 // BW floor x3
}

// Round 12
// 75.203 us; speedup vs baseline: 4.5438x; 4.5438x over previous
//
#include <hip/hip_runtime.h>
#include <math.h>

#define HEADS 8
#define C 256
#define NUM_STAR 4
#define SLOTS 32              // NUM_STAR * HEADS
#define RSQRT_DH 0.17677669529663688f   // 1/sqrt(32)
#define LN_EPS 1e-5f
#define PF 16                 // partitions per graph (grid = G*PF = 512 = 2/CU)
#define NT 32                 // nodes per block round
#define FS 260                // fbuf row stride (floats)
#define EP2 40                // e row stride (ushorts)

typedef __attribute__((ext_vector_type(8))) short short8;    // bf16x8 MFMA operand
typedef __attribute__((ext_vector_type(4))) float floatx4;   // f32x4 MFMA accum

typedef const unsigned int __attribute__((address_space(1)))* gp1_t;
typedef unsigned int __attribute__((address_space(3)))* lp3_t;

// f32 -> bf16 (RNE) top-16 (scalar)
__device__ __forceinline__ unsigned int f2b(float f) {
    unsigned int u = __float_as_uint(f);
    return (u + 0x7fffu + ((u >> 16) & 1u)) >> 16;
}
// packed f32x2 -> bf16x2 (RNE): lo -> [15:0], hi -> [31:16]
__device__ __forceinline__ unsigned int pk_bf16(float lo, float hi) {
    unsigned int r;
    asm("v_cvt_pk_bf16_f32 %0, %1, %2" : "=v"(r) : "v"(lo), "v"(hi));
    return r;
}
// async global->LDS, 16B/lane, NT cache policy (aux bit1): nodes is read-once,
// stream it past L3 allocation (testing whether the ~2.4 TB/s read wall is L3-path)
__device__ __forceinline__ void gld_lds16(const float* g, float* l) {
    __builtin_amdgcn_global_load_lds((gp1_t)(const void*)g, (lp3_t)(void*)l, 16, 0, 2);
}
// raw barrier: LDS-visible, does NOT drain vmcnt
__device__ __forceinline__ void block_sync_lds() {
    asm volatile("s_waitcnt lgkmcnt(0)" ::: "memory");
    __builtin_amdgcn_sched_barrier(0);
    __builtin_amdgcn_s_barrier();
    __builtin_amdgcn_sched_barrier(0);
}

// ---------------- star prep: ONE block per graph (4x weight-read amortization)
__global__ void k_star_prep(const float* __restrict__ stars,
                            const float* __restrict__ Wq_w, const float* __restrict__ Wq_b,
                            const float* __restrict__ Wk_w, const float* __restrict__ Wk_b,
                            unsigned short* __restrict__ U16, float* __restrict__ eself,
                            float* __restrict__ denom,
                            const int* __restrict__ batch, int N, int G,
                            int* __restrict__ gstart) {
    if ((int)blockIdx.x == G) {              // gstart block
        int g = threadIdx.x;
        if (g > G) return;
        if (g == 0) { gstart[0] = 0; return; }
        if (g == G) { gstart[G] = N; return; }
        int lo = 0, hi = N;
        while (lo < hi) {
            int mid = (lo + hi) >> 1;
            if (batch[mid] < g) lo = mid + 1; else hi = mid;
        }
        gstart[g] = lo;
        return;
    }

    __shared__ float xs[NUM_STAR][C];
    __shared__ float qv[NUM_STAR][C];
    __shared__ float kv[NUM_STAR][C];
    const int g = blockIdx.x;
    const int t = threadIdx.x;

    #pragma unroll
    for (int s = 0; s < NUM_STAR; ++s)
        xs[s][t] = stars[(g * NUM_STAR + s) * C + t];
    __syncthreads();

    // q,k row t for all 4 stars: weight rows read ONCE, reused 4x
    {
        float aq[NUM_STAR], ak[NUM_STAR];
        #pragma unroll
        for (int s = 0; s < NUM_STAR; ++s) { aq[s] = Wq_b[t]; ak[s] = Wk_b[t]; }
        const float* wq = Wq_w + (size_t)t * C;
        const float* wk = Wk_w + (size_t)t * C;
        #pragma unroll 2
        for (int j = 0; j < C; j += 4) {
            float4 a4 = *(const float4*)(wq + j);
            float4 b4 = *(const float4*)(wk + j);
            #pragma unroll
            for (int s = 0; s < NUM_STAR; ++s) {
                float4 x4 = *(const float4*)(&xs[s][j]);
                aq[s] += a4.x * x4.x + a4.y * x4.y + a4.z * x4.z + a4.w * x4.w;
                ak[s] += b4.x * x4.x + b4.y * x4.y + b4.z * x4.z + b4.w * x4.w;
            }
        }
        #pragma unroll
        for (int s = 0; s < NUM_STAR; ++s) { qv[s][t] = aq[s]; kv[s][t] = ak[s]; }
    }
    __syncthreads();

    // self scores per (star, head)
    #pragma unroll
    for (int s = 0; s < NUM_STAR; ++s) {
        float p = qv[s][t] * kv[s][t];
        #pragma unroll
        for (int off = 16; off; off >>= 1) p += __shfl_down(p, off, 32);
        if ((t & 31) == 0) {
            int h = t >> 5;
            float e = __expf(p * RSQRT_DH);
            eself[g * SLOTS + s * HEADS + h] = e;
            denom[g * SLOTS + s * HEADS + h] = e;   // init with self term
        }
    }

    // U for all 32 slots: Wk column element read once, reused for 4 stars
    {
        const int c = t;
        for (int h = 0; h < HEADS; ++h) {
            float u[NUM_STAR] = {0.f, 0.f, 0.f, 0.f};
            #pragma unroll
            for (int d = 0; d < 32; ++d) {
                float wkv = Wk_w[(size_t)(h * 32 + d) * C + c];
                #pragma unroll
                for (int s = 0; s < NUM_STAR; ++s)
                    u[s] += wkv * qv[s][h * 32 + d];
            }
            #pragma unroll
            for (int s = 0; s < NUM_STAR; ++s)
                U16[((size_t)g * SLOTS + s * HEADS + h) * C + c] =
                    (unsigned short)f2b(u[s] * RSQRT_DH);
        }
    }
}

// ---------------- fused MFMA kernel: DMA-staged, 32-node rounds -------------
// wave wv: QK^T slot-tile st=wv&1 on node-group ng=wv>>1; PV c-slice wv*64..+64
__global__ __launch_bounds__(256, 2)
void k_fused(const float* __restrict__ nodes, const unsigned short* __restrict__ U16,
             const int* __restrict__ gstart, float* __restrict__ denom,
             float* __restrict__ Ypart) {
    __shared__ float          fbuf[2][NT][FS];   // 66,560 B  f32 [buf][n][c]
    __shared__ unsigned short el[SLOTS * EP2];   //  2,560 B  e [s][n]

    const int g = blockIdx.x / PF, pb = blockIdx.x % PF;
    const int t = threadIdx.x;
    const int wv = t >> 6;        // wave 0..3
    const int l  = t & 63;
    const int lr = l & 15;
    const int q  = l >> 4;
    const int st = wv & 1;        // QK^T slot-tile
    const int ng = wv >> 1;       // QK^T node-group

    const int glo = gstart[g], ghi = gstart[g + 1];
    const int len = ghi - glo;
    const int Lb = (len + PF - 1) / PF;
    const int blo = glo + pb * Lb;
    const int bhi = min(blo + Lb, ghi);
    const int nrw = (bhi > blo) ? (bhi - blo + NT - 1) / NT : 0;

    const floatx4 z4 = {0.f, 0.f, 0.f, 0.f};
    floatx4 yacc[2][4];           // [st2][ct]: Y[st2*16+q*4+r][wv*64+ct*16+lr]
    #pragma unroll
    for (int a = 0; a < 2; ++a)
        #pragma unroll
        for (int b = 0; b < 4; ++b) yacc[a][b] = z4;
    float dsum[4];
    #pragma unroll
    for (int i = 0; i < 4; ++i) dsum[i] = 0.f;

    if (nrw > 0) {
        // ---- U_t fragments for own slot-tile only (32 VGPR) ----
        short8 ureg[8];
        {
            const unsigned short* ug = U16 + (size_t)g * SLOTS * C;
            #pragma unroll
            for (int kt = 0; kt < 8; ++kt)
                ureg[kt] = *(const short8*)&ug[(st * 16 + lr) * C + q * 8 + kt * 32];
        }
        asm volatile("s_waitcnt vmcnt(0)" ::: "memory");   // clean vmcnt base

        // DMA-issue round r into fbuf[r&1]: wave stages rows wv*8..wv*8+7
        auto issue = [&](int r) {
            const int buf = r & 1;
            #pragma unroll
            for (int i = 0; i < 8; ++i) {
                int row = wv * 8 + i;
                int gn = blo + r * NT + row;
                if (gn >= bhi) gn = blo;              // clamped dup; e masked to 0
                gld_lds16(nodes + (size_t)gn * C + l * 4, &fbuf[buf][row][0]);
            }
        };

        issue(0);
        issue(1);            // outstanding: 16 per wave

        for (int rd = 0; rd < nrw; ++rd) {
            const int cur = rd & 1;
            asm volatile("s_waitcnt vmcnt(8)" ::: "memory");  // rd landed (mine)
            __builtin_amdgcn_sched_barrier(0);
            __builtin_amdgcn_s_barrier();                     // everyone's rd landed
            __builtin_amdgcn_sched_barrier(0);

            // ---- QK^T: S[st*16+q*4+r][ng*16+lr] over K=256 ----
            floatx4 sacc = z4;
            {
                const float* xr = &fbuf[cur][ng * 16 + lr][q * 8];
                #pragma unroll
                for (int kt = 0; kt < 8; ++kt) {
                    float4 a4 = *(const float4*)(xr + kt * 32);
                    float4 b4 = *(const float4*)(xr + kt * 32 + 4);
                    short8 bx;
                    ((unsigned int*)&bx)[0] = pk_bf16(a4.x, a4.y);
                    ((unsigned int*)&bx)[1] = pk_bf16(a4.z, a4.w);
                    ((unsigned int*)&bx)[2] = pk_bf16(b4.x, b4.y);
                    ((unsigned int*)&bx)[3] = pk_bf16(b4.z, b4.w);
                    sacc = __builtin_amdgcn_mfma_f32_16x16x32_bf16(ureg[kt], bx, sacc, 0, 0, 0);
                }
            }
            // ---- exp + mask + denom + e write ([slot][n], n = ng*16+lr) ----
            {
                const bool valid = (blo + rd * NT + ng * 16 + lr) < bhi;
                #pragma unroll
                for (int r = 0; r < 4; ++r) {
                    float ev = valid ? __expf(sacc[r]) : 0.f;
                    dsum[r] += ev;
                    el[(st * 16 + q * 4 + r) * EP2 + ng * 16 + lr] = (unsigned short)f2b(ev);
                }
            }
            block_sync_lds();     // e complete; fbuf[cur] still stable

            // ---- PV: Y[s][c] += e[s][n] * x[n][c], K=32 (all real) ----
            {
                short8 pa0 = *(const short8*)&el[lr * EP2 + q * 8];
                short8 pa1 = *(const short8*)&el[(16 + lr) * EP2 + q * 8];
                #pragma unroll
                for (int ct = 0; ct < 4; ++ct) {
                    const int c = wv * 64 + ct * 16 + lr;
                    short8 bx;
                    const float* col = &fbuf[cur][q * 8][c];
                    ((unsigned int*)&bx)[0] = pk_bf16(col[0 * FS], col[1 * FS]);
                    ((unsigned int*)&bx)[1] = pk_bf16(col[2 * FS], col[3 * FS]);
                    ((unsigned int*)&bx)[2] = pk_bf16(col[4 * FS], col[5 * FS]);
                    ((unsigned int*)&bx)[3] = pk_bf16(col[6 * FS], col[7 * FS]);
                    yacc[0][ct] = __builtin_amdgcn_mfma_f32_16x16x32_bf16(pa0, bx, yacc[0][ct], 0, 0, 0);
                    yacc[1][ct] = __builtin_amdgcn_mfma_f32_16x16x32_bf16(pa1, bx, yacc[1][ct], 0, 0, 0);
                }
            }
            block_sync_lds();     // PV done reading fbuf[cur] + el
            issue(rd + 2);        // reuse buffer cur for round rd+2
        }

        asm volatile("s_waitcnt vmcnt(0)" ::: "memory");  // drain trailing DMA pre-exit

        // ---- denom: reduce over 16 node-lanes, atomics from lr==0 ----
        #pragma unroll
        for (int i = 0; i < 4; ++i) {
            float v = dsum[i];
            v += __shfl_xor(v, 1);
            v += __shfl_xor(v, 2);
            v += __shfl_xor(v, 4);
            v += __shfl_xor(v, 8);
            dsum[i] = v;
        }
        if (lr == 0) {
            #pragma unroll
            for (int r = 0; r < 4; ++r)
                atomicAdd(&denom[g * SLOTS + st * 16 + q * 4 + r], dsum[r]);
        }
    }

    // ---- write block partial (waves own disjoint c-slices; zero if nrw==0) --
    {
        float* yg = &Ypart[(((size_t)g * PF + pb) * SLOTS) * C];
        #pragma unroll
        for (int st2 = 0; st2 < 2; ++st2)
            #pragma unroll
            for (int ct = 0; ct < 4; ++ct)
                #pragma unroll
                for (int r = 0; r < 4; ++r)
                    yg[(st2 * 16 + q * 4 + r) * C + wv * 64 + ct * 16 + lr] = yacc[st2][ct][r];
    }
}

// ---------------- epilogue: out = LN(elu(Wv*(Ysum/denom + cself*x) + bv) + stars)
__global__ void k_epilogue(const float* __restrict__ stars,
                           const float* __restrict__ Wv_w, const float* __restrict__ Wv_b,
                           const float* __restrict__ gamma, const float* __restrict__ beta,
                           const float* __restrict__ Ypart, const float* __restrict__ eself,
                           const float* __restrict__ denom, float* __restrict__ out) {
    __shared__ float xs[C];
    __shared__ float yl[HEADS * C];
    __shared__ float cs[HEADS], ivd[HEADS], scl[HEADS];
    __shared__ float rb[8];

    const int gs = blockIdx.x;
    const int g = gs >> 2, s = gs & 3;
    const int t = threadIdx.x;

    xs[t] = stars[gs * C + t];
    if (t < HEADS) {
        float dn = denom[g * SLOTS + s * HEADS + t];
        float iv = 1.f / (dn + 1e-16f);
        ivd[t] = iv;
        cs[t] = eself[g * SLOTS + s * HEADS + t] * iv;
        scl[t] = dn * iv;
    }
    __syncthreads();

    for (int i = t; i < HEADS * C; i += 256) {
        int h = i >> 8, j = i & 255;
        float sum = 0.f;
        #pragma unroll
        for (int pbi = 0; pbi < PF; ++pbi)
            sum += Ypart[(((size_t)g * PF + pbi) * SLOTS + s * HEADS + h) * C + j];
        yl[i] = sum * ivd[h] + cs[h] * xs[j];
    }
    __syncthreads();

    const int c = t, h = c >> 5;
    float a = 0.f;
    const float* wv = Wv_w + (size_t)c * C;
    const float* yh = &yl[h * C];
    #pragma unroll 4
    for (int j = 0; j < C; j += 4) {
        float4 w4 = *(const float4*)(wv + j);
        float4 y4 = *(const float4*)(yh + j);
        a += w4.x * y4.x + w4.y * y4.y + w4.z * y4.z + w4.w * y4.w;
    }
    a += Wv_b[c] * scl[h];

    float v = a > 0.f ? a : (__expf(a) - 1.f);     // ELU
    float r = v + xs[c];                            // residual

    float ssum = r;
    #pragma unroll
    for (int off = 32; off; off >>= 1) ssum += __shfl_down(ssum, off, 64);
    const int wid = t >> 6, lane = t & 63;
    if (lane == 0) rb[wid] = ssum;
    __syncthreads();
    const float mu = (rb[0] + rb[1] + rb[2] + rb[3]) * (1.f / 256.f);
    const float d = r - mu;
    float vsum = d * d;
    #pragma unroll
    for (int off = 32; off; off >>= 1) vsum += __shfl_down(vsum, off, 64);
    if (lane == 0) rb[4 + wid] = vsum;
    __syncthreads();
    const float var = (rb[4] + rb[5] + rb[6] + rb[7]) * (1.f / 256.f);
    out[gs * C + c] = d * rsqrtf(var + LN_EPS) * gamma[c] + beta[c];
}

// ---------------------------------------------------------------------------
extern "C" void kernel_launch(void* const* d_in, const int* in_sizes, int n_in,
                              void* d_out, int out_size, void* d_ws, size_t ws_size,
                              hipStream_t stream) {
    const float* stars = (const float*)d_in[0];
    const float* nodes = (const float*)d_in[1];
    const int*   batch = (const int*)d_in[2];
    const float* Wq_w  = (const float*)d_in[3];
    const float* Wq_b  = (const float*)d_in[4];
    const float* Wk_w  = (const float*)d_in[5];
    const float* Wk_b  = (const float*)d_in[6];
    const float* Wv_w  = (const float*)d_in[7];
    const float* Wv_b  = (const float*)d_in[8];
    const float* gamma = (const float*)d_in[9];
    const float* beta  = (const float*)d_in[10];

    const int N = in_sizes[1] / C;
    const int G = in_sizes[0] / (NUM_STAR * C);

    unsigned short* U16 = (unsigned short*)d_ws;                    // G*SLOTS*C ush
    float* eself = (float*)((char*)d_ws + (size_t)G * SLOTS * C * 2);
    float* denom = eself + (size_t)G * SLOTS;
    float* Ypart = denom + (size_t)G * SLOTS;                       // G*PF*SLOTS*C f32
    int*   gstart = (int*)(Ypart + (size_t)G * PF * SLOTS * C);     // G+1

    float* out = (float*)d_out;

    k_star_prep<<<G + 1, 256, 0, stream>>>(stars, Wq_w, Wq_b, Wk_w, Wk_b,
                                           U16, eself, denom,
                                           batch, N, G, gstart);
    k_fused<<<G * PF, 256, 0, stream>>>(nodes, U16, gstart, denom, Ypart);
    k_epilogue<<<G * NUM_STAR, 256, 0, stream>>>(stars, Wv_w, Wv_b, gamma, beta,
                                                 Ypart, eself, denom, out);
}

// Round 13
// 73.994 us; speedup vs baseline: 4.6180x; 1.0163x over previous
//
#include <hip/hip_runtime.h>
#include <math.h>

#define HEADS 8
#define C 256
#define NUM_STAR 4
#define SLOTS 32              // NUM_STAR * HEADS
#define RSQRT_DH 0.17677669529663688f   // 1/sqrt(32)
#define LN_EPS 1e-5f
#define PF 16                 // partitions per graph (grid = G*PF = 512 = 2/CU)
#define NT 32                 // nodes per block round
#define FS 260                // fbuf row stride (floats)
#define EP2 40                // e row stride (ushorts)

typedef __attribute__((ext_vector_type(8))) short short8;    // bf16x8 MFMA operand
typedef __attribute__((ext_vector_type(4))) float floatx4;   // f32x4 MFMA accum

typedef const unsigned int __attribute__((address_space(1)))* gp1_t;
typedef unsigned int __attribute__((address_space(3)))* lp3_t;

// f32 -> bf16 (RNE) top-16 (scalar)
__device__ __forceinline__ unsigned int f2b(float f) {
    unsigned int u = __float_as_uint(f);
    return (u + 0x7fffu + ((u >> 16) & 1u)) >> 16;
}
// packed f32x2 -> bf16x2 (RNE): lo -> [15:0], hi -> [31:16]
__device__ __forceinline__ unsigned int pk_bf16(float lo, float hi) {
    unsigned int r;
    asm("v_cvt_pk_bf16_f32 %0, %1, %2" : "=v"(r) : "v"(lo), "v"(hi));
    return r;
}
// async global->LDS, 16B/lane, DEFAULT cache policy (aux=0).
// r12 measured: NT/stream policy (aux=2) forfeits ~47% L3 hits -> +7 us. Keep 0.
__device__ __forceinline__ void gld_lds16(const float* g, float* l) {
    __builtin_amdgcn_global_load_lds((gp1_t)(const void*)g, (lp3_t)(void*)l, 16, 0, 0);
}
// raw barrier: LDS-visible, does NOT drain vmcnt
__device__ __forceinline__ void block_sync_lds() {
    asm volatile("s_waitcnt lgkmcnt(0)" ::: "memory");
    __builtin_amdgcn_sched_barrier(0);
    __builtin_amdgcn_s_barrier();
    __builtin_amdgcn_sched_barrier(0);
}

// ---------------- star prep: ONE block per graph (4x weight-read amortization)
__global__ void k_star_prep(const float* __restrict__ stars,
                            const float* __restrict__ Wq_w, const float* __restrict__ Wq_b,
                            const float* __restrict__ Wk_w, const float* __restrict__ Wk_b,
                            unsigned short* __restrict__ U16, float* __restrict__ eself,
                            float* __restrict__ denom,
                            const int* __restrict__ batch, int N, int G,
                            int* __restrict__ gstart) {
    if ((int)blockIdx.x == G) {              // gstart block
        int g = threadIdx.x;
        if (g > G) return;
        if (g == 0) { gstart[0] = 0; return; }
        if (g == G) { gstart[G] = N; return; }
        int lo = 0, hi = N;
        while (lo < hi) {
            int mid = (lo + hi) >> 1;
            if (batch[mid] < g) lo = mid + 1; else hi = mid;
        }
        gstart[g] = lo;
        return;
    }

    __shared__ float xs[NUM_STAR][C];
    __shared__ float qv[NUM_STAR][C];
    __shared__ float kv[NUM_STAR][C];
    const int g = blockIdx.x;
    const int t = threadIdx.x;

    #pragma unroll
    for (int s = 0; s < NUM_STAR; ++s)
        xs[s][t] = stars[(g * NUM_STAR + s) * C + t];
    __syncthreads();

    // q,k row t for all 4 stars: weight rows read ONCE, reused 4x
    {
        float aq[NUM_STAR], ak[NUM_STAR];
        #pragma unroll
        for (int s = 0; s < NUM_STAR; ++s) { aq[s] = Wq_b[t]; ak[s] = Wk_b[t]; }
        const float* wq = Wq_w + (size_t)t * C;
        const float* wk = Wk_w + (size_t)t * C;
        #pragma unroll 2
        for (int j = 0; j < C; j += 4) {
            float4 a4 = *(const float4*)(wq + j);
            float4 b4 = *(const float4*)(wk + j);
            #pragma unroll
            for (int s = 0; s < NUM_STAR; ++s) {
                float4 x4 = *(const float4*)(&xs[s][j]);
                aq[s] += a4.x * x4.x + a4.y * x4.y + a4.z * x4.z + a4.w * x4.w;
                ak[s] += b4.x * x4.x + b4.y * x4.y + b4.z * x4.z + b4.w * x4.w;
            }
        }
        #pragma unroll
        for (int s = 0; s < NUM_STAR; ++s) { qv[s][t] = aq[s]; kv[s][t] = ak[s]; }
    }
    __syncthreads();

    // self scores per (star, head)
    #pragma unroll
    for (int s = 0; s < NUM_STAR; ++s) {
        float p = qv[s][t] * kv[s][t];
        #pragma unroll
        for (int off = 16; off; off >>= 1) p += __shfl_down(p, off, 32);
        if ((t & 31) == 0) {
            int h = t >> 5;
            float e = __expf(p * RSQRT_DH);
            eself[g * SLOTS + s * HEADS + h] = e;
            denom[g * SLOTS + s * HEADS + h] = e;   // init with self term
        }
    }

    // U for all 32 slots: Wk column element read once, reused for 4 stars
    {
        const int c = t;
        for (int h = 0; h < HEADS; ++h) {
            float u[NUM_STAR] = {0.f, 0.f, 0.f, 0.f};
            #pragma unroll
            for (int d = 0; d < 32; ++d) {
                float wkv = Wk_w[(size_t)(h * 32 + d) * C + c];
                #pragma unroll
                for (int s = 0; s < NUM_STAR; ++s)
                    u[s] += wkv * qv[s][h * 32 + d];
            }
            #pragma unroll
            for (int s = 0; s < NUM_STAR; ++s)
                U16[((size_t)g * SLOTS + s * HEADS + h) * C + c] =
                    (unsigned short)f2b(u[s] * RSQRT_DH);
        }
    }
}

// ---------------- fused MFMA kernel: DMA-staged, 32-node rounds -------------
// wave wv: QK^T slot-tile st=wv&1 on node-group ng=wv>>1; PV c-slice wv*64..+64
__global__ __launch_bounds__(256, 2)
void k_fused(const float* __restrict__ nodes, const unsigned short* __restrict__ U16,
             const int* __restrict__ gstart, float* __restrict__ denom,
             float* __restrict__ Ypart) {
    __shared__ float          fbuf[2][NT][FS];   // 66,560 B  f32 [buf][n][c]
    __shared__ unsigned short el[SLOTS * EP2];   //  2,560 B  e [s][n]

    const int g = blockIdx.x / PF, pb = blockIdx.x % PF;
    const int t = threadIdx.x;
    const int wv = t >> 6;        // wave 0..3
    const int l  = t & 63;
    const int lr = l & 15;
    const int q  = l >> 4;
    const int st = wv & 1;        // QK^T slot-tile
    const int ng = wv >> 1;       // QK^T node-group

    const int glo = gstart[g], ghi = gstart[g + 1];
    const int len = ghi - glo;
    const int Lb = (len + PF - 1) / PF;
    const int blo = glo + pb * Lb;
    const int bhi = min(blo + Lb, ghi);
    const int nrw = (bhi > blo) ? (bhi - blo + NT - 1) / NT : 0;

    const floatx4 z4 = {0.f, 0.f, 0.f, 0.f};
    floatx4 yacc[2][4];           // [st2][ct]: Y[st2*16+q*4+r][wv*64+ct*16+lr]
    #pragma unroll
    for (int a = 0; a < 2; ++a)
        #pragma unroll
        for (int b = 0; b < 4; ++b) yacc[a][b] = z4;
    float dsum[4];
    #pragma unroll
    for (int i = 0; i < 4; ++i) dsum[i] = 0.f;

    if (nrw > 0) {
        // ---- U_t fragments for own slot-tile only (32 VGPR) ----
        short8 ureg[8];
        {
            const unsigned short* ug = U16 + (size_t)g * SLOTS * C;
            #pragma unroll
            for (int kt = 0; kt < 8; ++kt)
                ureg[kt] = *(const short8*)&ug[(st * 16 + lr) * C + q * 8 + kt * 32];
        }
        asm volatile("s_waitcnt vmcnt(0)" ::: "memory");   // clean vmcnt base

        // DMA-issue round r into fbuf[r&1]: wave stages rows wv*8..wv*8+7
        auto issue = [&](int r) {
            const int buf = r & 1;
            #pragma unroll
            for (int i = 0; i < 8; ++i) {
                int row = wv * 8 + i;
                int gn = blo + r * NT + row;
                if (gn >= bhi) gn = blo;              // clamped dup; e masked to 0
                gld_lds16(nodes + (size_t)gn * C + l * 4, &fbuf[buf][row][0]);
            }
        };

        issue(0);
        issue(1);            // outstanding: 16 per wave

        for (int rd = 0; rd < nrw; ++rd) {
            const int cur = rd & 1;
            asm volatile("s_waitcnt vmcnt(8)" ::: "memory");  // rd landed (mine)
            __builtin_amdgcn_sched_barrier(0);
            __builtin_amdgcn_s_barrier();                     // everyone's rd landed
            __builtin_amdgcn_sched_barrier(0);

            // ---- QK^T: S[st*16+q*4+r][ng*16+lr] over K=256 ----
            floatx4 sacc = z4;
            {
                const float* xr = &fbuf[cur][ng * 16 + lr][q * 8];
                #pragma unroll
                for (int kt = 0; kt < 8; ++kt) {
                    float4 a4 = *(const float4*)(xr + kt * 32);
                    float4 b4 = *(const float4*)(xr + kt * 32 + 4);
                    short8 bx;
                    ((unsigned int*)&bx)[0] = pk_bf16(a4.x, a4.y);
                    ((unsigned int*)&bx)[1] = pk_bf16(a4.z, a4.w);
                    ((unsigned int*)&bx)[2] = pk_bf16(b4.x, b4.y);
                    ((unsigned int*)&bx)[3] = pk_bf16(b4.z, b4.w);
                    sacc = __builtin_amdgcn_mfma_f32_16x16x32_bf16(ureg[kt], bx, sacc, 0, 0, 0);
                }
            }
            // ---- exp + mask + denom + e write ([slot][n], n = ng*16+lr) ----
            {
                const bool valid = (blo + rd * NT + ng * 16 + lr) < bhi;
                #pragma unroll
                for (int r = 0; r < 4; ++r) {
                    float ev = valid ? __expf(sacc[r]) : 0.f;
                    dsum[r] += ev;
                    el[(st * 16 + q * 4 + r) * EP2 + ng * 16 + lr] = (unsigned short)f2b(ev);
                }
            }
            block_sync_lds();     // e complete; fbuf[cur] still stable

            // ---- PV: Y[s][c] += e[s][n] * x[n][c], K=32 (all real) ----
            {
                short8 pa0 = *(const short8*)&el[lr * EP2 + q * 8];
                short8 pa1 = *(const short8*)&el[(16 + lr) * EP2 + q * 8];
                #pragma unroll
                for (int ct = 0; ct < 4; ++ct) {
                    const int c = wv * 64 + ct * 16 + lr;
                    short8 bx;
                    const float* col = &fbuf[cur][q * 8][c];
                    ((unsigned int*)&bx)[0] = pk_bf16(col[0 * FS], col[1 * FS]);
                    ((unsigned int*)&bx)[1] = pk_bf16(col[2 * FS], col[3 * FS]);
                    ((unsigned int*)&bx)[2] = pk_bf16(col[4 * FS], col[5 * FS]);
                    ((unsigned int*)&bx)[3] = pk_bf16(col[6 * FS], col[7 * FS]);
                    yacc[0][ct] = __builtin_amdgcn_mfma_f32_16x16x32_bf16(pa0, bx, yacc[0][ct], 0, 0, 0);
                    yacc[1][ct] = __builtin_amdgcn_mfma_f32_16x16x32_bf16(pa1, bx, yacc[1][ct], 0, 0, 0);
                }
            }
            block_sync_lds();     // PV done reading fbuf[cur] + el
            issue(rd + 2);        // reuse buffer cur for round rd+2
        }

        asm volatile("s_waitcnt vmcnt(0)" ::: "memory");  // drain trailing DMA pre-exit

        // ---- denom: reduce over 16 node-lanes, atomics from lr==0 ----
        #pragma unroll
        for (int i = 0; i < 4; ++i) {
            float v = dsum[i];
            v += __shfl_xor(v, 1);
            v += __shfl_xor(v, 2);
            v += __shfl_xor(v, 4);
            v += __shfl_xor(v, 8);
            dsum[i] = v;
        }
        if (lr == 0) {
            #pragma unroll
            for (int r = 0; r < 4; ++r)
                atomicAdd(&denom[g * SLOTS + st * 16 + q * 4 + r], dsum[r]);
        }
    }

    // ---- write block partial (waves own disjoint c-slices; zero if nrw==0) --
    {
        float* yg = &Ypart[(((size_t)g * PF + pb) * SLOTS) * C];
        #pragma unroll
        for (int st2 = 0; st2 < 2; ++st2)
            #pragma unroll
            for (int ct = 0; ct < 4; ++ct)
                #pragma unroll
                for (int r = 0; r < 4; ++r)
                    yg[(st2 * 16 + q * 4 + r) * C + wv * 64 + ct * 16 + lr] = yacc[st2][ct][r];
    }
}

// ---------------- epilogue: out = LN(elu(Wv*(Ysum/denom + cself*x) + bv) + stars)
__global__ void k_epilogue(const float* __restrict__ stars,
                           const float* __restrict__ Wv_w, const float* __restrict__ Wv_b,
                           const float* __restrict__ gamma, const float* __restrict__ beta,
                           const float* __restrict__ Ypart, const float* __restrict__ eself,
                           const float* __restrict__ denom, float* __restrict__ out) {
    __shared__ float xs[C];
    __shared__ float yl[HEADS * C];
    __shared__ float cs[HEADS], ivd[HEADS], scl[HEADS];
    __shared__ float rb[8];

    const int gs = blockIdx.x;
    const int g = gs >> 2, s = gs & 3;
    const int t = threadIdx.x;

    xs[t] = stars[gs * C + t];
    if (t < HEADS) {
        float dn = denom[g * SLOTS + s * HEADS + t];
        float iv = 1.f / (dn + 1e-16f);
        ivd[t] = iv;
        cs[t] = eself[g * SLOTS + s * HEADS + t] * iv;
        scl[t] = dn * iv;
    }
    __syncthreads();

    for (int i = t; i < HEADS * C; i += 256) {
        int h = i >> 8, j = i & 255;
        float sum = 0.f;
        #pragma unroll
        for (int pbi = 0; pbi < PF; ++pbi)
            sum += Ypart[(((size_t)g * PF + pbi) * SLOTS + s * HEADS + h) * C + j];
        yl[i] = sum * ivd[h] + cs[h] * xs[j];
    }
    __syncthreads();

    const int c = t, h = c >> 5;
    float a = 0.f;
    const float* wv = Wv_w + (size_t)c * C;
    const float* yh = &yl[h * C];
    #pragma unroll 4
    for (int j = 0; j < C; j += 4) {
        float4 w4 = *(const float4*)(wv + j);
        float4 y4 = *(const float4*)(yh + j);
        a += w4.x * y4.x + w4.y * y4.y + w4.z * y4.z + w4.w * y4.w;
    }
    a += Wv_b[c] * scl[h];

    float v = a > 0.f ? a : (__expf(a) - 1.f);     // ELU
    float r = v + xs[c];                            // residual

    float ssum = r;
    #pragma unroll
    for (int off = 32; off; off >>= 1) ssum += __shfl_down(ssum, off, 64);
    const int wid = t >> 6, lane = t & 63;
    if (lane == 0) rb[wid] = ssum;
    __syncthreads();
    const float mu = (rb[0] + rb[1] + rb[2] + rb[3]) * (1.f / 256.f);
    const float d = r - mu;
    float vsum = d * d;
    #pragma unroll
    for (int off = 32; off; off >>= 1) vsum += __shfl_down(vsum, off, 64);
    if (lane == 0) rb[4 + wid] = vsum;
    __syncthreads();
    const float var = (rb[4] + rb[5] + rb[6] + rb[7]) * (1.f / 256.f);
    out[gs * C + c] = d * rsqrtf(var + LN_EPS) * gamma[c] + beta[c];
}

// ---------------------------------------------------------------------------
extern "C" void kernel_launch(void* const* d_in, const int* in_sizes, int n_in,
                              void* d_out, int out_size, void* d_ws, size_t ws_size,
                              hipStream_t stream) {
    const float* stars = (const float*)d_in[0];
    const float* nodes = (const float*)d_in[1];
    const int*   batch = (const int*)d_in[2];
    const float* Wq_w  = (const float*)d_in[3];
    const float* Wq_b  = (const float*)d_in[4];
    const float* Wk_w  = (const float*)d_in[5];
    const float* Wk_b  = (const float*)d_in[6];
    const float* Wv_w  = (const float*)d_in[7];
    const float* Wv_b  = (const float*)d_in[8];
    const float* gamma = (const float*)d_in[9];
    const float* beta  = (const float*)d_in[10];

    const int N = in_sizes[1] / C;
    const int G = in_sizes[0] / (NUM_STAR * C);

    unsigned short* U16 = (unsigned short*)d_ws;                    // G*SLOTS*C ush
    float* eself = (float*)((char*)d_ws + (size_t)G * SLOTS * C * 2);
    float* denom = eself + (size_t)G * SLOTS;
    float* Ypart = denom + (size_t)G * SLOTS;                       // G*PF*SLOTS*C f32
    int*   gstart = (int*)(Ypart + (size_t)G * PF * SLOTS * C);     // G+1

    float* out = (float*)d_out;

    k_star_prep<<<G + 1, 256, 0, stream>>>(stars, Wq_w, Wq_b, Wk_w, Wk_b,
                                           U16, eself, denom,
                                           batch, N, G, gstart);
    k_fused<<<G * PF, 256, 0, stream>>>(nodes, U16, gstart, denom, Ypart);
    k_epilogue<<<G * NUM_STAR, 256, 0, stream>>>(stars, Wv_w, Wv_b, gamma, beta,
                                                 Ypart, eself, denom, out);
}

// Round 14
// 65.559 us; speedup vs baseline: 5.2122x; 1.1287x over previous
//
#include <hip/hip_runtime.h>
#include <math.h>

#define HEADS 8
#define C 256
#define NUM_STAR 4
#define SLOTS 32              // NUM_STAR * HEADS
#define RSQRT_DH 0.17677669529663688f   // 1/sqrt(32)
#define LN_EPS 1e-5f
#define PF 16                 // partitions per graph (grid = G*PF = 512 = 2/CU)
#define NT 32                 // nodes per block round
#define FS 260                // fbuf row stride (floats)
#define EP2 40                // e row stride (ushorts)

typedef __attribute__((ext_vector_type(8))) short short8;    // bf16x8 MFMA operand
typedef __attribute__((ext_vector_type(4))) float floatx4;   // f32x4 MFMA accum

typedef const unsigned int __attribute__((address_space(1)))* gp1_t;
typedef unsigned int __attribute__((address_space(3)))* lp3_t;

// f32 -> bf16 (RNE) top-16 (scalar)
__device__ __forceinline__ unsigned int f2b(float f) {
    unsigned int u = __float_as_uint(f);
    return (u + 0x7fffu + ((u >> 16) & 1u)) >> 16;
}
__device__ __forceinline__ float b2f(unsigned short v) {
    return __uint_as_float(((unsigned int)v) << 16);
}
// packed f32x2 -> bf16x2 (RNE): lo -> [15:0], hi -> [31:16]
__device__ __forceinline__ unsigned int pk_bf16(float lo, float hi) {
    unsigned int r;
    asm("v_cvt_pk_bf16_f32 %0, %1, %2" : "=v"(r) : "v"(lo), "v"(hi));
    return r;
}
// async global->LDS, 16B/lane, DEFAULT cache policy (aux=0; r12: NT policy -7us)
__device__ __forceinline__ void gld_lds16(const float* g, float* l) {
    __builtin_amdgcn_global_load_lds((gp1_t)(const void*)g, (lp3_t)(void*)l, 16, 0, 0);
}
// raw barrier: LDS-visible, does NOT drain vmcnt
__device__ __forceinline__ void block_sync_lds() {
    asm volatile("s_waitcnt lgkmcnt(0)" ::: "memory");
    __builtin_amdgcn_sched_barrier(0);
    __builtin_amdgcn_s_barrier();
    __builtin_amdgcn_sched_barrier(0);
}

// ---------------- star prep: one block per STAR (r10 config; r13 showed the
// merged per-graph variant costs +5.6us from lost parallelism) ---------------
__global__ void k_star_prep(const float* __restrict__ stars,
                            const float* __restrict__ Wq_w, const float* __restrict__ Wq_b,
                            const float* __restrict__ Wk_w, const float* __restrict__ Wk_b,
                            unsigned short* __restrict__ U16, float* __restrict__ eself,
                            float* __restrict__ denom,
                            const int* __restrict__ batch, int N, int G,
                            int* __restrict__ gstart) {
    if (blockIdx.x == gridDim.x - 1) {       // gstart block
        int g = threadIdx.x;
        if (g > G) return;
        if (g == 0) { gstart[0] = 0; return; }
        if (g == G) { gstart[G] = N; return; }
        int lo = 0, hi = N;
        while (lo < hi) {
            int mid = (lo + hi) >> 1;
            if (batch[mid] < g) lo = mid + 1; else hi = mid;
        }
        gstart[g] = lo;
        return;
    }

    __shared__ float xs[C];
    __shared__ float qv[C];
    __shared__ float kv[C];
    const int gs = blockIdx.x;           // g*4 + s
    const int g = gs >> 2, s = gs & 3;
    const int t = threadIdx.x;

    xs[t] = stars[gs * C + t];
    __syncthreads();

    float aq = Wq_b[t], ak = Wk_b[t];
    const float* wq = Wq_w + (size_t)t * C;
    const float* wk = Wk_w + (size_t)t * C;
    #pragma unroll 4
    for (int j = 0; j < C; j += 4) {
        float4 x4 = *(const float4*)(xs + j);
        float4 a4 = *(const float4*)(wq + j);
        aq += a4.x * x4.x + a4.y * x4.y + a4.z * x4.z + a4.w * x4.w;
        float4 b4 = *(const float4*)(wk + j);
        ak += b4.x * x4.x + b4.y * x4.y + b4.z * x4.z + b4.w * x4.w;
    }
    qv[t] = aq; kv[t] = ak;
    __syncthreads();

    {   // self score per head
        float p = qv[t] * kv[t];
        #pragma unroll
        for (int off = 16; off; off >>= 1) p += __shfl_down(p, off, 32);
        if ((t & 31) == 0) {
            int h = t >> 5;
            float e = __expf(p * RSQRT_DH);
            eself[g * SLOTS + s * HEADS + h] = e;
            denom[g * SLOTS + s * HEADS + h] = e;   // init with self term
        }
    }

    // U_t bf16: U16[g][slot=s*8+h][c]
    {
        const int c = t;
        #pragma unroll
        for (int h = 0; h < HEADS; ++h) {
            float u = 0.f;
            #pragma unroll
            for (int d = 0; d < 32; ++d)
                u += Wk_w[(size_t)(h * 32 + d) * C + c] * qv[h * 32 + d];
            U16[((size_t)g * SLOTS + s * HEADS + h) * C + c] =
                (unsigned short)f2b(u * RSQRT_DH);
        }
    }
}

// ---------------- fused MFMA kernel: DMA-staged, 32-node rounds -------------
// wave wv: QK^T slot-tile st=wv&1 on node-group ng=wv>>1; PV c-slice wv*64..+64
__global__ __launch_bounds__(256, 2)
void k_fused(const float* __restrict__ nodes, const unsigned short* __restrict__ U16,
             const int* __restrict__ gstart, float* __restrict__ denom,
             unsigned short* __restrict__ Ypart16) {
    __shared__ float          fbuf[2][NT][FS];   // 66,560 B  f32 [buf][n][c]
    __shared__ unsigned short el[SLOTS * EP2];   //  2,560 B  e [s][n]

    const int g = blockIdx.x / PF, pb = blockIdx.x % PF;
    const int t = threadIdx.x;
    const int wv = t >> 6;        // wave 0..3
    const int l  = t & 63;
    const int lr = l & 15;
    const int q  = l >> 4;
    const int st = wv & 1;        // QK^T slot-tile
    const int ng = wv >> 1;       // QK^T node-group

    const int glo = gstart[g], ghi = gstart[g + 1];
    const int len = ghi - glo;
    const int Lb = (len + PF - 1) / PF;
    const int blo = glo + pb * Lb;
    const int bhi = min(blo + Lb, ghi);
    const int nrw = (bhi > blo) ? (bhi - blo + NT - 1) / NT : 0;

    const floatx4 z4 = {0.f, 0.f, 0.f, 0.f};
    floatx4 yacc[2][4];           // [st2][ct]: Y[st2*16+q*4+r][wv*64+ct*16+lr]
    #pragma unroll
    for (int a = 0; a < 2; ++a)
        #pragma unroll
        for (int b = 0; b < 4; ++b) yacc[a][b] = z4;
    float dsum[4];
    #pragma unroll
    for (int i = 0; i < 4; ++i) dsum[i] = 0.f;

    if (nrw > 0) {
        // ---- U_t fragments for own slot-tile only (32 VGPR) ----
        short8 ureg[8];
        {
            const unsigned short* ug = U16 + (size_t)g * SLOTS * C;
            #pragma unroll
            for (int kt = 0; kt < 8; ++kt)
                ureg[kt] = *(const short8*)&ug[(st * 16 + lr) * C + q * 8 + kt * 32];
        }
        asm volatile("s_waitcnt vmcnt(0)" ::: "memory");   // clean vmcnt base

        // DMA-issue round r into fbuf[r&1]: wave stages rows wv*8..wv*8+7
        auto issue = [&](int r) {
            const int buf = r & 1;
            #pragma unroll
            for (int i = 0; i < 8; ++i) {
                int row = wv * 8 + i;
                int gn = blo + r * NT + row;
                if (gn >= bhi) gn = blo;              // clamped dup; e masked to 0
                gld_lds16(nodes + (size_t)gn * C + l * 4, &fbuf[buf][row][0]);
            }
        };

        issue(0);
        issue(1);            // outstanding: 16 per wave

        for (int rd = 0; rd < nrw; ++rd) {
            const int cur = rd & 1;
            asm volatile("s_waitcnt vmcnt(8)" ::: "memory");  // rd landed (mine)
            __builtin_amdgcn_sched_barrier(0);
            __builtin_amdgcn_s_barrier();                     // everyone's rd landed
            __builtin_amdgcn_sched_barrier(0);

            // ---- QK^T: S[st*16+q*4+r][ng*16+lr] over K=256 ----
            floatx4 sacc = z4;
            {
                const float* xr = &fbuf[cur][ng * 16 + lr][q * 8];
                #pragma unroll
                for (int kt = 0; kt < 8; ++kt) {
                    float4 a4 = *(const float4*)(xr + kt * 32);
                    float4 b4 = *(const float4*)(xr + kt * 32 + 4);
                    short8 bx;
                    ((unsigned int*)&bx)[0] = pk_bf16(a4.x, a4.y);
                    ((unsigned int*)&bx)[1] = pk_bf16(a4.z, a4.w);
                    ((unsigned int*)&bx)[2] = pk_bf16(b4.x, b4.y);
                    ((unsigned int*)&bx)[3] = pk_bf16(b4.z, b4.w);
                    sacc = __builtin_amdgcn_mfma_f32_16x16x32_bf16(ureg[kt], bx, sacc, 0, 0, 0);
                }
            }
            // ---- exp + mask + denom + e write ([slot][n], n = ng*16+lr) ----
            {
                const bool valid = (blo + rd * NT + ng * 16 + lr) < bhi;
                #pragma unroll
                for (int r = 0; r < 4; ++r) {
                    float ev = valid ? __expf(sacc[r]) : 0.f;
                    dsum[r] += ev;
                    el[(st * 16 + q * 4 + r) * EP2 + ng * 16 + lr] = (unsigned short)f2b(ev);
                }
            }
            block_sync_lds();     // e complete; fbuf[cur] still stable

            // ---- PV: Y[s][c] += e[s][n] * x[n][c], K=32 (all real) ----
            {
                short8 pa0 = *(const short8*)&el[lr * EP2 + q * 8];
                short8 pa1 = *(const short8*)&el[(16 + lr) * EP2 + q * 8];
                #pragma unroll
                for (int ct = 0; ct < 4; ++ct) {
                    const int c = wv * 64 + ct * 16 + lr;
                    short8 bx;
                    const float* col = &fbuf[cur][q * 8][c];
                    ((unsigned int*)&bx)[0] = pk_bf16(col[0 * FS], col[1 * FS]);
                    ((unsigned int*)&bx)[1] = pk_bf16(col[2 * FS], col[3 * FS]);
                    ((unsigned int*)&bx)[2] = pk_bf16(col[4 * FS], col[5 * FS]);
                    ((unsigned int*)&bx)[3] = pk_bf16(col[6 * FS], col[7 * FS]);
                    yacc[0][ct] = __builtin_amdgcn_mfma_f32_16x16x32_bf16(pa0, bx, yacc[0][ct], 0, 0, 0);
                    yacc[1][ct] = __builtin_amdgcn_mfma_f32_16x16x32_bf16(pa1, bx, yacc[1][ct], 0, 0, 0);
                }
            }
            block_sync_lds();     // PV done reading fbuf[cur] + el
            issue(rd + 2);        // reuse buffer cur for round rd+2
        }

        asm volatile("s_waitcnt vmcnt(0)" ::: "memory");  // drain trailing DMA pre-exit

        // ---- denom: reduce over 16 node-lanes, atomics from lr==0 ----
        #pragma unroll
        for (int i = 0; i < 4; ++i) {
            float v = dsum[i];
            v += __shfl_xor(v, 1);
            v += __shfl_xor(v, 2);
            v += __shfl_xor(v, 4);
            v += __shfl_xor(v, 8);
            dsum[i] = v;
        }
        if (lr == 0) {
            #pragma unroll
            for (int r = 0; r < 4; ++r)
                atomicAdd(&denom[g * SLOTS + st * 16 + q * 4 + r], dsum[r]);
        }
    }

    // ---- write block partial as bf16 (halves the Ypart round-trip traffic;
    //      error ~1e-4 at output after /denom + Wv — negligible vs 0.086 thr) --
    {
        unsigned short* yg = &Ypart16[(((size_t)g * PF + pb) * SLOTS) * C];
        #pragma unroll
        for (int st2 = 0; st2 < 2; ++st2)
            #pragma unroll
            for (int ct = 0; ct < 4; ++ct)
                #pragma unroll
                for (int r = 0; r < 4; ++r)
                    yg[(st2 * 16 + q * 4 + r) * C + wv * 64 + ct * 16 + lr] =
                        (unsigned short)f2b(yacc[st2][ct][r]);
    }
}

// ---------------- epilogue: out = LN(elu(Wv*(Ysum/denom + cself*x) + bv) + stars)
__global__ void k_epilogue(const float* __restrict__ stars,
                           const float* __restrict__ Wv_w, const float* __restrict__ Wv_b,
                           const float* __restrict__ gamma, const float* __restrict__ beta,
                           const unsigned short* __restrict__ Ypart16,
                           const float* __restrict__ eself,
                           const float* __restrict__ denom, float* __restrict__ out) {
    __shared__ float xs[C];
    __shared__ float yl[HEADS * C];
    __shared__ float cs[HEADS], ivd[HEADS], scl[HEADS];
    __shared__ float rb[8];

    const int gs = blockIdx.x;
    const int g = gs >> 2, s = gs & 3;
    const int t = threadIdx.x;

    xs[t] = stars[gs * C + t];
    if (t < HEADS) {
        float dn = denom[g * SLOTS + s * HEADS + t];
        float iv = 1.f / (dn + 1e-16f);
        ivd[t] = iv;
        cs[t] = eself[g * SLOTS + s * HEADS + t] * iv;
        scl[t] = dn * iv;
    }
    __syncthreads();

    for (int i = t; i < HEADS * C; i += 256) {
        int h = i >> 8, j = i & 255;
        float sum = 0.f;
        #pragma unroll
        for (int pbi = 0; pbi < PF; ++pbi)
            sum += b2f(Ypart16[(((size_t)g * PF + pbi) * SLOTS + s * HEADS + h) * C + j]);
        yl[i] = sum * ivd[h] + cs[h] * xs[j];
    }
    __syncthreads();

    const int c = t, h = c >> 5;
    float a = 0.f;
    const float* wv = Wv_w + (size_t)c * C;
    const float* yh = &yl[h * C];
    #pragma unroll 4
    for (int j = 0; j < C; j += 4) {
        float4 w4 = *(const float4*)(wv + j);
        float4 y4 = *(const float4*)(yh + j);
        a += w4.x * y4.x + w4.y * y4.y + w4.z * y4.z + w4.w * y4.w;
    }
    a += Wv_b[c] * scl[h];

    float v = a > 0.f ? a : (__expf(a) - 1.f);     // ELU
    float r = v + xs[c];                            // residual

    float ssum = r;
    #pragma unroll
    for (int off = 32; off; off >>= 1) ssum += __shfl_down(ssum, off, 64);
    const int wid = t >> 6, lane = t & 63;
    if (lane == 0) rb[wid] = ssum;
    __syncthreads();
    const float mu = (rb[0] + rb[1] + rb[2] + rb[3]) * (1.f / 256.f);
    const float d = r - mu;
    float vsum = d * d;
    #pragma unroll
    for (int off = 32; off; off >>= 1) vsum += __shfl_down(vsum, off, 64);
    if (lane == 0) rb[4 + wid] = vsum;
    __syncthreads();
    const float var = (rb[4] + rb[5] + rb[6] + rb[7]) * (1.f / 256.f);
    out[gs * C + c] = d * rsqrtf(var + LN_EPS) * gamma[c] + beta[c];
}

// ---------------------------------------------------------------------------
extern "C" void kernel_launch(void* const* d_in, const int* in_sizes, int n_in,
                              void* d_out, int out_size, void* d_ws, size_t ws_size,
                              hipStream_t stream) {
    const float* stars = (const float*)d_in[0];
    const float* nodes = (const float*)d_in[1];
    const int*   batch = (const int*)d_in[2];
    const float* Wq_w  = (const float*)d_in[3];
    const float* Wq_b  = (const float*)d_in[4];
    const float* Wk_w  = (const float*)d_in[5];
    const float* Wk_b  = (const float*)d_in[6];
    const float* Wv_w  = (const float*)d_in[7];
    const float* Wv_b  = (const float*)d_in[8];
    const float* gamma = (const float*)d_in[9];
    const float* beta  = (const float*)d_in[10];

    const int N = in_sizes[1] / C;
    const int G = in_sizes[0] / (NUM_STAR * C);

    unsigned short* U16 = (unsigned short*)d_ws;                    // G*SLOTS*C ush
    float* eself = (float*)((char*)d_ws + (size_t)G * SLOTS * C * 2);
    float* denom = eself + (size_t)G * SLOTS;
    unsigned short* Ypart16 = (unsigned short*)(denom + (size_t)G * SLOTS); // G*PF*SLOTS*C ush
    int*   gstart = (int*)(Ypart16 + (size_t)G * PF * SLOTS * C);   // G+1

    float* out = (float*)d_out;

    k_star_prep<<<G * NUM_STAR + 1, 256, 0, stream>>>(stars, Wq_w, Wq_b, Wk_w, Wk_b,
                                                      U16, eself, denom,
                                                      batch, N, G, gstart);
    k_fused<<<G * PF, 256, 0, stream>>>(nodes, U16, gstart, denom, Ypart16);
    k_epilogue<<<G * NUM_STAR, 256, 0, stream>>>(stars, Wv_w, Wv_b, gamma, beta,
                                                 Ypart16, eself, denom, out);
}

// Round 15
// 64.088 us; speedup vs baseline: 5.3318x; 1.0229x over previous
//
#include <hip/hip_runtime.h>
#include <math.h>

#define HEADS 8
#define C 256
#define NUM_STAR 4
#define SLOTS 32              // NUM_STAR * HEADS
#define RSQRT_DH 0.17677669529663688f   // 1/sqrt(32)
#define LN_EPS 1e-5f
#define PF 8                  // partitions per graph (grid = G*PF = 256 = 1 block/CU)
#define NT 32                 // nodes per round
#define FS 260                // fbuf row stride (floats)
#define EP2 40                // e row stride (ushorts)

typedef __attribute__((ext_vector_type(8))) short short8;    // bf16x8 MFMA operand
typedef __attribute__((ext_vector_type(4))) float floatx4;   // f32x4 MFMA accum

typedef const unsigned int __attribute__((address_space(1)))* gp1_t;
typedef unsigned int __attribute__((address_space(3)))* lp3_t;

// f32 -> bf16 (RNE) top-16 (scalar)
__device__ __forceinline__ unsigned int f2b(float f) {
    unsigned int u = __float_as_uint(f);
    return (u + 0x7fffu + ((u >> 16) & 1u)) >> 16;
}
__device__ __forceinline__ float b2f(unsigned short v) {
    return __uint_as_float(((unsigned int)v) << 16);
}
// packed f32x2 -> bf16x2 (RNE): lo -> [15:0], hi -> [31:16]
__device__ __forceinline__ unsigned int pk_bf16(float lo, float hi) {
    unsigned int r;
    asm("v_cvt_pk_bf16_f32 %0, %1, %2" : "=v"(r) : "v"(lo), "v"(hi));
    return r;
}
// async global->LDS, 16B/lane, DEFAULT cache policy (r12: NT policy -7us)
__device__ __forceinline__ void gld_lds16(const float* g, float* l) {
    __builtin_amdgcn_global_load_lds((gp1_t)(const void*)g, (lp3_t)(void*)l, 16, 0, 0);
}
// raw barrier: LDS-visible, does NOT drain vmcnt
__device__ __forceinline__ void block_sync_lds() {
    asm volatile("s_waitcnt lgkmcnt(0)" ::: "memory");
    __builtin_amdgcn_sched_barrier(0);
    __builtin_amdgcn_s_barrier();
    __builtin_amdgcn_sched_barrier(0);
}

// ---------------- star prep: one block per STAR (r13: merged variant -5.6us) -
__global__ void k_star_prep(const float* __restrict__ stars,
                            const float* __restrict__ Wq_w, const float* __restrict__ Wq_b,
                            const float* __restrict__ Wk_w, const float* __restrict__ Wk_b,
                            unsigned short* __restrict__ U16, float* __restrict__ eself,
                            float* __restrict__ denom,
                            const int* __restrict__ batch, int N, int G,
                            int* __restrict__ gstart) {
    if (blockIdx.x == gridDim.x - 1) {       // gstart block
        int g = threadIdx.x;
        if (g > G) return;
        if (g == 0) { gstart[0] = 0; return; }
        if (g == G) { gstart[G] = N; return; }
        int lo = 0, hi = N;
        while (lo < hi) {
            int mid = (lo + hi) >> 1;
            if (batch[mid] < g) lo = mid + 1; else hi = mid;
        }
        gstart[g] = lo;
        return;
    }

    __shared__ float xs[C];
    __shared__ float qv[C];
    __shared__ float kv[C];
    const int gs = blockIdx.x;           // g*4 + s
    const int g = gs >> 2, s = gs & 3;
    const int t = threadIdx.x;

    xs[t] = stars[gs * C + t];
    __syncthreads();

    float aq = Wq_b[t], ak = Wk_b[t];
    const float* wq = Wq_w + (size_t)t * C;
    const float* wk = Wk_w + (size_t)t * C;
    #pragma unroll 4
    for (int j = 0; j < C; j += 4) {
        float4 x4 = *(const float4*)(xs + j);
        float4 a4 = *(const float4*)(wq + j);
        aq += a4.x * x4.x + a4.y * x4.y + a4.z * x4.z + a4.w * x4.w;
        float4 b4 = *(const float4*)(wk + j);
        ak += b4.x * x4.x + b4.y * x4.y + b4.z * x4.z + b4.w * x4.w;
    }
    qv[t] = aq; kv[t] = ak;
    __syncthreads();

    {   // self score per head
        float p = qv[t] * kv[t];
        #pragma unroll
        for (int off = 16; off; off >>= 1) p += __shfl_down(p, off, 32);
        if ((t & 31) == 0) {
            int h = t >> 5;
            float e = __expf(p * RSQRT_DH);
            eself[g * SLOTS + s * HEADS + h] = e;
            denom[g * SLOTS + s * HEADS + h] = e;   // init with self term
        }
    }

    // U_t bf16: U16[g][slot=s*8+h][c]
    {
        const int c = t;
        #pragma unroll
        for (int h = 0; h < HEADS; ++h) {
            float u = 0.f;
            #pragma unroll
            for (int d = 0; d < 32; ++d)
                u += Wk_w[(size_t)(h * 32 + d) * C + c] * qv[h * 32 + d];
            U16[((size_t)g * SLOTS + s * HEADS + h) * C + c] =
                (unsigned short)f2b(u * RSQRT_DH);
        }
    }
}

// ---------------- fused MFMA kernel: producer-consumer wave specialization ---
// 8 waves: wv 0-3 = QK^T(rd) producers (st=wv&1, ng=wv>>1);
//          wv 4-7 = PV(rd-1) consumers (c-slice (wv-4)*64).
// 4-deep fbuf ring, ONE barrier/round, DMA issued right after the barrier.
__global__ __launch_bounds__(512, 1)
void k_fused(const float* __restrict__ nodes, const unsigned short* __restrict__ U16,
             const int* __restrict__ gstart, float* __restrict__ denom,
             unsigned short* __restrict__ Ypart16) {
    __shared__ float          fbuf[4][NT][FS];      // 133,120 B f32 ring
    __shared__ unsigned short el[2][SLOTS * EP2];   //   5,120 B e ping-pong

    const int g = blockIdx.x / PF, pb = blockIdx.x % PF;
    const int t = threadIdx.x;
    const int wv = t >> 6;        // wave 0..7
    const int l  = t & 63;
    const int lr = l & 15;
    const int q  = l >> 4;
    const int st = wv & 1;        // QK^T slot-tile (wv<4)
    const int ng = (wv >> 1) & 1; // QK^T node-group (wv<4)

    const int glo = gstart[g], ghi = gstart[g + 1];
    const int len = ghi - glo;
    const int Lb = (len + PF - 1) / PF;
    const int blo = glo + pb * Lb;
    const int bhi = min(blo + Lb, ghi);
    const int nrw = (bhi > blo) ? (bhi - blo + NT - 1) / NT : 0;

    const floatx4 z4 = {0.f, 0.f, 0.f, 0.f};
    floatx4 yacc[2][4];           // PV waves: Y[st2*16+q*4+r][(wv-4)*64+ct*16+lr]
    #pragma unroll
    for (int a = 0; a < 2; ++a)
        #pragma unroll
        for (int b = 0; b < 4; ++b) yacc[a][b] = z4;
    float dsum[4];
    #pragma unroll
    for (int i = 0; i < 4; ++i) dsum[i] = 0.f;

    if (nrw > 0) {
        // ---- U_t fragments (QK waves only; 32 VGPR) ----
        short8 ureg[8];
        if (wv < 4) {
            const unsigned short* ug = U16 + (size_t)g * SLOTS * C;
            #pragma unroll
            for (int kt = 0; kt < 8; ++kt)
                ureg[kt] = *(const short8*)&ug[(st * 16 + lr) * C + q * 8 + kt * 32];
        }
        asm volatile("s_waitcnt vmcnt(0)" ::: "memory");   // clean vmcnt baseline

        // DMA-issue round r into ring slot r&3: wave stages rows wv*4..wv*4+3
        auto issue = [&](int r) {
            const int buf = r & 3;
            #pragma unroll
            for (int i = 0; i < 4; ++i) {
                int row = wv * 4 + i;
                int gn = blo + r * NT + row;
                if (gn >= bhi) gn = blo;              // clamped dup; e masked to 0
                gld_lds16(nodes + (size_t)gn * C + l * 4, &fbuf[buf][row][0]);
            }
        };

        issue(0);
        issue(1);            // outstanding: 8 per wave (2 rounds x 4)

        for (int rd = 0; rd <= nrw; ++rd) {
            if (rd < nrw) {
                // my 4 loads for round rd landed (leaves rd+1's 4 in flight)
                asm volatile("s_waitcnt vmcnt(4)" ::: "memory");
                __builtin_amdgcn_sched_barrier(0);
            }
            block_sync_lds();     // rd landed globally; rd-2's buffer free; e visible

            if (rd < nrw) {
                issue(rd + 2);    // into free ring slot (rd+2)&3, ASAP

                if (wv < 4) {
                    // ---- QK^T(rd): S[st*16+q*4+r][ng*16+lr] over K=256 ----
                    floatx4 sacc = z4;
                    {
                        const float* xr = &fbuf[rd & 3][ng * 16 + lr][q * 8];
                        #pragma unroll
                        for (int kt = 0; kt < 8; ++kt) {
                            float4 a4 = *(const float4*)(xr + kt * 32);
                            float4 b4 = *(const float4*)(xr + kt * 32 + 4);
                            short8 bx;
                            ((unsigned int*)&bx)[0] = pk_bf16(a4.x, a4.y);
                            ((unsigned int*)&bx)[1] = pk_bf16(a4.z, a4.w);
                            ((unsigned int*)&bx)[2] = pk_bf16(b4.x, b4.y);
                            ((unsigned int*)&bx)[3] = pk_bf16(b4.z, b4.w);
                            sacc = __builtin_amdgcn_mfma_f32_16x16x32_bf16(ureg[kt], bx, sacc, 0, 0, 0);
                        }
                    }
                    // exp + mask + denom + e[rd&1] write
                    const bool valid = (blo + rd * NT + ng * 16 + lr) < bhi;
                    unsigned short* ew = el[rd & 1];
                    #pragma unroll
                    for (int r = 0; r < 4; ++r) {
                        float ev = valid ? __expf(sacc[r]) : 0.f;
                        dsum[r] += ev;
                        ew[(st * 16 + q * 4 + r) * EP2 + ng * 16 + lr] = (unsigned short)f2b(ev);
                    }
                }
            }

            if (rd >= 1 && wv >= 4) {
                // ---- PV(rd-1): Y[s][c] += e[s][n] * x[n][c], K=32 ----
                const unsigned short* ep = el[(rd - 1) & 1];
                const float (*fb)[FS] = fbuf[(rd - 1) & 3];
                short8 pa0 = *(const short8*)&ep[lr * EP2 + q * 8];
                short8 pa1 = *(const short8*)&ep[(16 + lr) * EP2 + q * 8];
                #pragma unroll
                for (int ct = 0; ct < 4; ++ct) {
                    const int c = (wv - 4) * 64 + ct * 16 + lr;
                    short8 bx;
                    const float* col = &fb[q * 8][c];
                    ((unsigned int*)&bx)[0] = pk_bf16(col[0 * FS], col[1 * FS]);
                    ((unsigned int*)&bx)[1] = pk_bf16(col[2 * FS], col[3 * FS]);
                    ((unsigned int*)&bx)[2] = pk_bf16(col[4 * FS], col[5 * FS]);
                    ((unsigned int*)&bx)[3] = pk_bf16(col[6 * FS], col[7 * FS]);
                    yacc[0][ct] = __builtin_amdgcn_mfma_f32_16x16x32_bf16(pa0, bx, yacc[0][ct], 0, 0, 0);
                    yacc[1][ct] = __builtin_amdgcn_mfma_f32_16x16x32_bf16(pa1, bx, yacc[1][ct], 0, 0, 0);
                }
            }
        }

        asm volatile("s_waitcnt vmcnt(0)" ::: "memory");  // drain trailing DMA

        // ---- denom (QK waves): reduce over 16 node-lanes, atomics from lr==0
        if (wv < 4) {
            #pragma unroll
            for (int i = 0; i < 4; ++i) {
                float v = dsum[i];
                v += __shfl_xor(v, 1);
                v += __shfl_xor(v, 2);
                v += __shfl_xor(v, 4);
                v += __shfl_xor(v, 8);
                dsum[i] = v;
            }
            if (lr == 0 && ng == 0) {
                #pragma unroll
                for (int r = 0; r < 4; ++r)
                    atomicAdd(&denom[g * SLOTS + st * 16 + q * 4 + r], dsum[r]);
            }
            if (lr == 0 && ng == 1) {
                #pragma unroll
                for (int r = 0; r < 4; ++r)
                    atomicAdd(&denom[g * SLOTS + st * 16 + q * 4 + r], dsum[r]);
            }
        }
    }

    // ---- write block partial as bf16 (PV waves own disjoint c-slices;
    //      zero-fills when nrw==0) ----
    if (wv >= 4) {
        unsigned short* yg = &Ypart16[(((size_t)g * PF + pb) * SLOTS) * C];
        const int cw = (wv - 4) * 64;
        #pragma unroll
        for (int st2 = 0; st2 < 2; ++st2)
            #pragma unroll
            for (int ct = 0; ct < 4; ++ct)
                #pragma unroll
                for (int r = 0; r < 4; ++r)
                    yg[(st2 * 16 + q * 4 + r) * C + cw + ct * 16 + lr] =
                        (unsigned short)f2b(yacc[st2][ct][r]);
    }
}

// ---------------- epilogue: out = LN(elu(Wv*(Ysum/denom + cself*x) + bv) + stars)
__global__ void k_epilogue(const float* __restrict__ stars,
                           const float* __restrict__ Wv_w, const float* __restrict__ Wv_b,
                           const float* __restrict__ gamma, const float* __restrict__ beta,
                           const unsigned short* __restrict__ Ypart16,
                           const float* __restrict__ eself,
                           const float* __restrict__ denom, float* __restrict__ out) {
    __shared__ float xs[C];
    __shared__ float yl[HEADS * C];
    __shared__ float cs[HEADS], ivd[HEADS], scl[HEADS];
    __shared__ float rb[8];

    const int gs = blockIdx.x;
    const int g = gs >> 2, s = gs & 3;
    const int t = threadIdx.x;

    xs[t] = stars[gs * C + t];
    if (t < HEADS) {
        float dn = denom[g * SLOTS + s * HEADS + t];
        float iv = 1.f / (dn + 1e-16f);
        ivd[t] = iv;
        cs[t] = eself[g * SLOTS + s * HEADS + t] * iv;
        scl[t] = dn * iv;
    }
    __syncthreads();

    for (int i = t; i < HEADS * C; i += 256) {
        int h = i >> 8, j = i & 255;
        float sum = 0.f;
        #pragma unroll
        for (int pbi = 0; pbi < PF; ++pbi)
            sum += b2f(Ypart16[(((size_t)g * PF + pbi) * SLOTS + s * HEADS + h) * C + j]);
        yl[i] = sum * ivd[h] + cs[h] * xs[j];
    }
    __syncthreads();

    const int c = t, h = c >> 5;
    float a = 0.f;
    const float* wv = Wv_w + (size_t)c * C;
    const float* yh = &yl[h * C];
    #pragma unroll 4
    for (int j = 0; j < C; j += 4) {
        float4 w4 = *(const float4*)(wv + j);
        float4 y4 = *(const float4*)(yh + j);
        a += w4.x * y4.x + w4.y * y4.y + w4.z * y4.z + w4.w * y4.w;
    }
    a += Wv_b[c] * scl[h];

    float v = a > 0.f ? a : (__expf(a) - 1.f);     // ELU
    float r = v + xs[c];                            // residual

    float ssum = r;
    #pragma unroll
    for (int off = 32; off; off >>= 1) ssum += __shfl_down(ssum, off, 64);
    const int wid = t >> 6, lane = t & 63;
    if (lane == 0) rb[wid] = ssum;
    __syncthreads();
    const float mu = (rb[0] + rb[1] + rb[2] + rb[3]) * (1.f / 256.f);
    const float d = r - mu;
    float vsum = d * d;
    #pragma unroll
    for (int off = 32; off; off >>= 1) vsum += __shfl_down(vsum, off, 64);
    if (lane == 0) rb[4 + wid] = vsum;
    __syncthreads();
    const float var = (rb[4] + rb[5] + rb[6] + rb[7]) * (1.f / 256.f);
    out[gs * C + c] = d * rsqrtf(var + LN_EPS) * gamma[c] + beta[c];
}

// ---------------------------------------------------------------------------
extern "C" void kernel_launch(void* const* d_in, const int* in_sizes, int n_in,
                              void* d_out, int out_size, void* d_ws, size_t ws_size,
                              hipStream_t stream) {
    const float* stars = (const float*)d_in[0];
    const float* nodes = (const float*)d_in[1];
    const int*   batch = (const int*)d_in[2];
    const float* Wq_w  = (const float*)d_in[3];
    const float* Wq_b  = (const float*)d_in[4];
    const float* Wk_w  = (const float*)d_in[5];
    const float* Wk_b  = (const float*)d_in[6];
    const float* Wv_w  = (const float*)d_in[7];
    const float* Wv_b  = (const float*)d_in[8];
    const float* gamma = (const float*)d_in[9];
    const float* beta  = (const float*)d_in[10];

    const int N = in_sizes[1] / C;
    const int G = in_sizes[0] / (NUM_STAR * C);

    unsigned short* U16 = (unsigned short*)d_ws;                    // G*SLOTS*C ush
    float* eself = (float*)((char*)d_ws + (size_t)G * SLOTS * C * 2);
    float* denom = eself + (size_t)G * SLOTS;
    unsigned short* Ypart16 = (unsigned short*)(denom + (size_t)G * SLOTS); // G*PF*SLOTS*C ush
    int*   gstart = (int*)(Ypart16 + (size_t)G * PF * SLOTS * C);   // G+1

    float* out = (float*)d_out;

    k_star_prep<<<G * NUM_STAR + 1, 256, 0, stream>>>(stars, Wq_w, Wq_b, Wk_w, Wk_b,
                                                      U16, eself, denom,
                                                      batch, N, G, gstart);
    k_fused<<<G * PF, 512, 0, stream>>>(nodes, U16, gstart, denom, Ypart16);
    k_epilogue<<<G * NUM_STAR, 256, 0, stream>>>(stars, Wv_w, Wv_b, gamma, beta,
                                                 Ypart16, eself, denom, out);
}